// Round 3
// baseline (29941.449 us; speedup 1.0000x reference)
//
#include <hip/hip_runtime.h>

namespace {
constexpr int BB   = 32;    // batch
constexpr int TT   = 2048;  // time
constexpr int HH   = 512;   // hidden (== D)
constexpr int NBLK = 128;   // blocks per layer
constexpr int RING = 4;     // ring slots
constexpr int YSZ  = BB * TT * HH;
constexpr int HFO  = YSZ;
constexpr int CFO  = YSZ + 2 * BB * HH;
constexpr int FSTR = 32;    // flag stride in ints (128 B -> one L3 line per flag)
}

typedef float f32x4 __attribute__((ext_vector_type(4)));

__device__ __forceinline__ float sigf(float v)  { return 1.0f / (1.0f + __expf(-v)); }
__device__ __forceinline__ float tanh_(float v) { return 1.0f - 2.0f / (__expf(2.0f * v) + 1.0f); }

__device__ __forceinline__ int uswz(int b, int kc) {
  return (b << 7) + (kc ^ ((b & 7) << 2) ^ (((kc >> 5) & 3) << 2));
}
__device__ __forceinline__ int wswz(int row, int k) {
  return (row << 10) + (k ^ ((row >> 2) << 3) ^ (((k >> 5) & 3) << 2));
}

// Coherent (agent-scope) accesses: bypass per-CU L1 / per-XCD L2, hit shared L3.
__device__ __forceinline__ f32x4 ld_x4_coh(const float* p) {
  f32x4 r;
  asm volatile("global_load_dwordx4 %0, %1, off sc1" : "=v"(r) : "v"(p) : "memory");
  return r;
}
__device__ __forceinline__ void st_coh(float* p, float v) {
  __hip_atomic_store(p, v, __ATOMIC_RELAXED, __HIP_MEMORY_SCOPE_AGENT);
}
__device__ __forceinline__ void st_flag(int* p, int v) {
  __hip_atomic_store(p, v, __ATOMIC_RELAXED, __HIP_MEMORY_SCOPE_AGENT);
}
// Per-lane spin: each lane polls its own flag; wave exits when all lanes pass.
__device__ __forceinline__ void poll_ge(const int* p, int need) {
  while (__hip_atomic_load(p, __ATOMIC_RELAXED, __HIP_MEMORY_SCOPE_AGENT) < need)
    __builtin_amdgcn_s_sleep(1);
}

__global__ __launch_bounds__(256, 1) void lstm_persist(
    const float* __restrict__ x,
    const float* __restrict__ Wih0, const float* __restrict__ Whh0,
    const float* __restrict__ bih0, const float* __restrict__ bhh0,
    const float* __restrict__ Wih1, const float* __restrict__ Whh1,
    const float* __restrict__ bih1, const float* __restrict__ bhh1,
    const float* __restrict__ h0c, const float* __restrict__ c0c,
    float* __restrict__ out, float* __restrict__ ring, float* __restrict__ ring1,
    int* __restrict__ flags0, int* __restrict__ flags1)
{
  __shared__ __align__(16) float Wsh[16 * 1024];
  __shared__ __align__(16) float ubuf[BB * 128];
  float* gbuf = ubuf;  // alias: 512-float gate buffer between (C)/(E) barriers

  const int tid   = (int)threadIdx.x;
  const int layer = (int)(blockIdx.x >> 7);
  const int lb    = (int)(blockIdx.x & (NBLK - 1));
  const int j0    = lb << 2;

  const float* Wih = layer ? Wih1 : Wih0;
  const float* Whh = layer ? Whh1 : Whh0;
  const float* bih = layer ? bih1 : bih0;
  const float* bhh = layer ? bhh1 : bhh0;

  for (int idx = tid; idx < 16 * 1024; idx += 256) {
    const int row = idx >> 10;
    const int k   = idx & 1023;
    const int rg  = ((row >> 2) << 9) + j0 + (row & 3);
    const float v = (k < 512) ? Wih[(rg << 9) + k] : Whh[(rg << 9) + (k - 512)];
    Wsh[wswz(row, k)] = v;
  }

  float creg = 0.0f;
  float bias_[4] = {0.f, 0.f, 0.f, 0.f};
  if (tid < 128) {
    const int jj = tid & 3;
    creg = c0c[layer * HH + j0 + jj];
#pragma unroll
    for (int g = 0; g < 4; ++g) {
      const int rg = (g << 9) + j0 + jj;
      bias_[g] = bih[rg] + bhh[rg];
    }
  }

  const int kt = tid & 7;
  const int rt = (tid >> 3) & 3;
  const int bt = tid >> 5;

  f32x4 r4[4];  // staging prefetch registers (loop-carried across chunks)

#pragma unroll 1
  for (int s = 0; s < TT; ++s) {
    f32x4 acc[4][4];
#pragma unroll
    for (int ri = 0; ri < 4; ++ri)
#pragma unroll
      for (int bi = 0; bi < 4; ++bi)
        acc[ri][bi] = (f32x4){0.f, 0.f, 0.f, 0.f};

    // Logical chunk order: L0 = [x0..x3, h0..h3]; L1 = [h1_0..h1_3, y0_0..y0_3].
    auto load_chunk = [&](int i) {
#pragma unroll
      for (int j = 0; j < 4; ++j) {
        const int f   = tid + (j << 8);
        const int b   = f >> 5;
        const int kc4 = (f & 31) << 2;
        if (layer == 0) {
          if (i < 4) {
            r4[j] = *(const f32x4*)(x + ((size_t)((b << 11) + s) << 9) + (i << 7) + kc4);
          } else if (s == 0) {
            r4[j] = *(const f32x4*)(h0c + ((i - 4) << 7) + kc4);
          } else {
            r4[j] = ld_x4_coh(ring + ((((s - 1) & (RING - 1)) * BB + b) << 9) + ((i - 4) << 7) + kc4);
          }
        } else {
          if (i < 4) {
            if (s == 0) r4[j] = *(const f32x4*)(h0c + HH + (i << 7) + kc4);
            else        r4[j] = ld_x4_coh(ring1 + ((((s - 1) & (RING - 1)) * BB + b) << 9) + (i << 7) + kc4);
          } else {
            r4[j] = ld_x4_coh(ring + (((s & (RING - 1)) * BB + b) << 9) + ((i - 4) << 7) + kc4);
          }
        }
      }
    };
    auto compute = [&](int i) {
      const int kc = (layer == 0) ? i : ((i < 4) ? 4 + i : i - 4);
#pragma unroll
      for (int kk = 0; kk < 16; kk += 4) {
        const int kc4 = (kt << 4) + kk;
        f32x4 u[4], w[4];
#pragma unroll
        for (int bi = 0; bi < 4; ++bi)
          u[bi] = *(const f32x4*)(ubuf + uswz((bt << 2) + bi, kc4));
        const int kx = (kc << 7) + kc4;
#pragma unroll
        for (int ri = 0; ri < 4; ++ri)
          w[ri] = *(const f32x4*)(Wsh + wswz((rt << 2) + ri, kx));
#pragma unroll
        for (int ri = 0; ri < 4; ++ri)
#pragma unroll
          for (int bi = 0; bi < 4; ++bi) {
            acc[ri][bi].x = fmaf(u[bi].x, w[ri].x, acc[ri][bi].x);
            acc[ri][bi].y = fmaf(u[bi].y, w[ri].y, acc[ri][bi].y);
            acc[ri][bi].z = fmaf(u[bi].z, w[ri].z, acc[ri][bi].z);
            acc[ri][bi].w = fmaf(u[bi].w, w[ri].w, acc[ri][bi].w);
          }
      }
    };

    // L1 step-start dependency: own h1[s-1] — all 128 L1 flags, polled in parallel.
    if (layer == 1 && s > 0) {
      if (tid < 128) poll_ge(flags1 + (tid << 5), s);
      __builtin_amdgcn_s_barrier();
      __builtin_amdgcn_sched_barrier(0);
    }

    load_chunk(0);

#pragma unroll 1
    for (int i = 0; i < 8; ++i) {
      __builtin_amdgcn_s_barrier();                 // (A) ubuf free
      __builtin_amdgcn_sched_barrier(0);
      asm volatile("s_waitcnt vmcnt(0)" ::: "memory");  // chunk-i loads landed
      __builtin_amdgcn_sched_barrier(0);
#pragma unroll
      for (int j = 0; j < 4; ++j) {
        const int f   = tid + (j << 8);
        const int b   = f >> 5;
        const int kc4 = (f & 31) << 2;
        *(f32x4*)(ubuf + uswz(b, kc4)) = r4[j];
      }
      if (i < 7) {
        if (i == 3) {  // cross-dependent half: parallel per-lane flag polls
          if (layer == 0) {
            if (tid < 128) {
              if (s > 0) poll_ge(flags0 + (tid << 5), s);            // h[s-1] ready
            } else if (s >= RING) {
              poll_ge(flags1 + ((tid - 128) << 5), s - RING + 1);    // ring slot free
            }
          } else {
            if (tid < 128) poll_ge(flags0 + (tid << 5), s + 1);      // y0[s] ready
          }
          __builtin_amdgcn_s_barrier();             // (P) all producers confirmed
          __builtin_amdgcn_sched_barrier(0);
        }
        load_chunk(i + 1);                          // prefetch flies during compute
      }
      asm volatile("s_waitcnt lgkmcnt(0)" ::: "memory");
      __builtin_amdgcn_sched_barrier(0);
      __builtin_amdgcn_s_barrier();                 // (B) ubuf visible
      __builtin_amdgcn_sched_barrier(0);
      compute(i);
    }

    // k-split reduction (lanes xor 1,2,4 sum the 8-way split)
    float rv[4][4];
#pragma unroll
    for (int ri = 0; ri < 4; ++ri)
#pragma unroll
      for (int bi = 0; bi < 4; ++bi) {
        float v = (acc[ri][bi].x + acc[ri][bi].y) + (acc[ri][bi].z + acc[ri][bi].w);
        v += __shfl_xor(v, 1, 64);
        v += __shfl_xor(v, 2, 64);
        v += __shfl_xor(v, 4, 64);
        rv[ri][bi] = v;
      }
    __builtin_amdgcn_s_barrier();                   // (C) compute(7) reads done
    __builtin_amdgcn_sched_barrier(0);
    if (kt == 0) {
#pragma unroll
      for (int ri = 0; ri < 4; ++ri)
#pragma unroll
        for (int bi = 0; bi < 4; ++bi)
          gbuf[(((rt << 2) + ri) << 5) + (bt << 2) + bi] = rv[ri][bi];
    }
    asm volatile("s_waitcnt lgkmcnt(0)" ::: "memory");
    __builtin_amdgcn_sched_barrier(0);
    __builtin_amdgcn_s_barrier();                   // (D) gbuf visible
    __builtin_amdgcn_sched_barrier(0);

    if (tid < 128) {
      const int jj = tid & 3;
      const int b  = tid >> 2;
      const float gi = gbuf[((0 + jj) << 5) + b] + bias_[0];
      const float gf = gbuf[((4 + jj) << 5) + b] + bias_[1];
      const float gg = gbuf[((8 + jj) << 5) + b] + bias_[2];
      const float go = gbuf[((12 + jj) << 5) + b] + bias_[3];
      const float cn = sigf(gf) * creg + sigf(gi) * tanh_(gg);
      const float hn = sigf(go) * tanh_(cn);
      creg = cn;
      const int j = j0 + jj;
      if (layer == 0) {
        st_coh(ring + (((s & (RING - 1)) * BB + b) << 9) + j, hn);
        if (s == TT - 1) out[(size_t)HFO + (b << 9) + j] = hn;
      } else {
        out[((size_t)((b << 11) + s) << 9) + j] = hn;
        st_coh(ring1 + (((s & (RING - 1)) * BB + b) << 9) + j, hn);
        if (s == TT - 1) out[(size_t)HFO + ((BB + b) << 9) + j] = hn;
      }
    }
    __syncthreads();  // (E) per-wave vmcnt(0) drain: h/y stores visible at L3
    if (tid == 0) {
      // one uncontended store to this block's own flag line (no RMW fan-in)
      st_flag((layer ? flags1 : flags0) + (lb << 5), s + 1);
    }
  }

  if (tid < 128) {
    const int jj = tid & 3;
    const int b  = tid >> 2;
    out[(size_t)CFO + ((layer * BB + b) << 9) + (j0 + jj)] = creg;
  }
}

extern "C" void kernel_launch(void* const* d_in, const int* in_sizes, int n_in,
                              void* d_out, int out_size, void* d_ws, size_t ws_size,
                              hipStream_t stream) {
  (void)in_sizes; (void)n_in; (void)out_size; (void)ws_size;
  const float* x    = (const float*)d_in[0];
  const float* Wih0 = (const float*)d_in[1];
  const float* Whh0 = (const float*)d_in[2];
  const float* bih0 = (const float*)d_in[3];
  const float* bhh0 = (const float*)d_in[4];
  const float* Wih1 = (const float*)d_in[5];
  const float* Whh1 = (const float*)d_in[6];
  const float* bih1 = (const float*)d_in[7];
  const float* bhh1 = (const float*)d_in[8];
  const float* h0   = (const float*)d_in[9];
  const float* c0   = (const float*)d_in[10];

  float* out    = (float*)d_out;
  float* ring   = (float*)d_ws;                            // 256 KB
  float* ring1  = (float*)((char*)d_ws + (256 << 10));     // 256 KB
  int*   flags0 = (int*)((char*)d_ws + (512 << 10));       // 128 flags x 128 B
  int*   flags1 = (int*)((char*)d_ws + (528 << 10));       // 128 flags x 128 B

  // flags must be zero every call (graph replays don't re-poison)
  hipMemsetAsync(flags0, 0, 32 << 10, stream);

  hipLaunchKernelGGL(lstm_persist, dim3(2 * NBLK), dim3(256), 0, stream,
                     x, Wih0, Whh0, bih0, bhh0, Wih1, Whh1, bih1, bhh1,
                     h0, c0, out, ring, ring1, flags0, flags1);
}

// Round 4
// 28503.766 us; speedup vs baseline: 1.0504x; 1.0504x over previous
//
#include <hip/hip_runtime.h>

namespace {
constexpr int BB   = 32;    // batch
constexpr int TT   = 2048;  // time
constexpr int HH   = 512;   // hidden (== D)
constexpr int NBLK = 128;   // blocks per layer
constexpr int RING = 4;     // ring slots
constexpr int YSZ  = BB * TT * HH;
constexpr int HFO  = YSZ;
constexpr int CFO  = YSZ + 2 * BB * HH;
}

typedef float f32x4 __attribute__((ext_vector_type(4)));

__device__ __forceinline__ float sigf(float v)  { return 1.0f / (1.0f + __expf(-v)); }
__device__ __forceinline__ float tanh_(float v) { return 1.0f - 2.0f / (__expf(2.0f * v) + 1.0f); }

// plain cached 16B load (read-only inputs: x, h0)
__device__ __forceinline__ f32x4 ld_x4(const float* p) {
  f32x4 r;
  asm volatile("global_load_dwordx4 %0, %1, off" : "=v"(r) : "v"(p) : "memory");
  return r;
}
// agent-coherent 16B load (sc1: bypass L1/L2, hit shared coherence point)
__device__ __forceinline__ f32x4 ld_x4_coh(const float* p) {
  f32x4 r;
  asm volatile("global_load_dwordx4 %0, %1, off sc1" : "=v"(r) : "v"(p) : "memory");
  return r;
}
__device__ __forceinline__ void st_coh(float* p, float v) {
  __hip_atomic_store(p, v, __ATOMIC_RELAXED, __HIP_MEMORY_SCOPE_AGENT);
}
__device__ __forceinline__ void poll_lane(const int* f, int need) {
  while (__hip_atomic_load(f, __ATOMIC_RELAXED, __HIP_MEMORY_SCOPE_AGENT) < need)
    __builtin_amdgcn_s_sleep(1);
}

#define VMCNT4() do { asm volatile("s_waitcnt vmcnt(4)" ::: "memory"); __builtin_amdgcn_sched_barrier(0); } while (0)
#define VMCNT0() do { asm volatile("s_waitcnt vmcnt(0)" ::: "memory"); __builtin_amdgcn_sched_barrier(0); } while (0)
#define LGKM0()  do { asm volatile("s_waitcnt lgkmcnt(0)" ::: "memory"); __builtin_amdgcn_sched_barrier(0); } while (0)
#define BAR()    do { __builtin_amdgcn_s_barrier(); __builtin_amdgcn_sched_barrier(0); } while (0)

__global__ __launch_bounds__(512, 1) void lstm_persist(
    const float* __restrict__ x,
    const float* __restrict__ Wih0, const float* __restrict__ Whh0,
    const float* __restrict__ bih0, const float* __restrict__ bhh0,
    const float* __restrict__ Wih1, const float* __restrict__ Whh1,
    const float* __restrict__ bih1, const float* __restrict__ bhh1,
    const float* __restrict__ h0c, const float* __restrict__ c0c,
    float* __restrict__ out, float* __restrict__ ring, float* __restrict__ ring1,
    int* __restrict__ flags0, int* __restrict__ flags1)
{
  // LDS: W' 64 KB + double-buffered input slots 2x32 KB = 128 KB (1 block/CU).
  __shared__ __align__(16) float Wsh[16 * 1024];
  __shared__ __align__(16) float ubuf[2 * 32 * 256];
  float* gbuf = ubuf;  // alias of slot A; live only between bar5 and bar6

  const int tid   = (int)threadIdx.x;
  const int layer = (int)(blockIdx.x >> 7);
  const int lb    = (int)(blockIdx.x & (NBLK - 1));
  const int j0    = lb << 2;
  const int lane  = tid & 63;
  const int wg    = tid >> 6;          // wave id 0..7
  const int k4    = lane << 2;         // this lane's f32x4 within a 256-k chunk
  const int R0    = (wg & 1) << 3;     // 8-row group
  const int B0    = (wg >> 1) << 3;    // 8-batch group

  const float* Wih = layer ? Wih1 : Wih0;
  const float* Whh = layer ? Whh1 : Whh0;
  const float* bih = layer ? bih1 : bih0;
  const float* bhh = layer ? bhh1 : bhh0;
  int* fl_own = layer ? flags1 : flags0;   // h producers are always the own layer

  // ---- prologue: weights -> LDS (linear, conflict-free), bias, c0 ----
  for (int idx = tid; idx < 16 * 1024; idx += 512) {
    const int row = idx >> 10;           // 0..15 = gate*4 + jj
    const int k   = idx & 1023;
    const int rg  = ((row >> 2) << 9) + j0 + (row & 3);
    Wsh[(row << 10) + k] = (k < 512) ? Wih[(rg << 9) + k] : Whh[(rg << 9) + (k - 512)];
  }
  float creg = 0.0f;
  float bias_[4] = {0.f, 0.f, 0.f, 0.f};
  if (tid < 128) {
    const int jj = tid & 3;
    creg = c0c[layer * HH + j0 + jj];
#pragma unroll
    for (int g = 0; g < 4; ++g) {
      const int rg = (g << 9) + j0 + jj;
      bias_[g] = bih[rg] + bhh[rg];
    }
  }

  // chunk loader: 4 x f32x4 per thread; each f32x4 = 4 h-columns = ONE producer block
  auto issue = [&](f32x4* r, int c, int ss) {
#pragma unroll
    for (int i = 0; i < 4; ++i) {
      const int b = (i << 3) + wg;
      if (layer == 0) {
        if (c < 2)
          r[i] = ld_x4(x + ((size_t)((b << 11) + ss) << 9) + (c << 8) + k4);
        else if (ss == 0)
          r[i] = ld_x4(h0c + ((c - 2) << 8) + k4);
        else
          r[i] = ld_x4_coh(ring + (size_t)((((ss - 1) & 3) << 5) + b) * 512 + ((c - 2) << 8) + k4);
      } else {
        if (c < 2)
          r[i] = ld_x4_coh(ring + (size_t)(((ss & 3) << 5) + b) * 512 + (c << 8) + k4);
        else if (ss == 0)
          r[i] = ld_x4(h0c + 512 + ((c - 2) << 8) + k4);
        else
          r[i] = ld_x4_coh(ring1 + (size_t)((((ss - 1) & 3) << 5) + b) * 512 + ((c - 2) << 8) + k4);
      }
    }
  };
  auto stage = [&](int slot, const f32x4* r) {
    float* sp = ubuf + (slot << 13);
#pragma unroll
    for (int i = 0; i < 4; ++i)                       // contiguous 1024 B per wave: conflict-free
      *(f32x4*)(sp + ((((i << 3) + wg)) << 8) + k4) = r[i];
  };

  float red[64];  // 8 rows x 8 batches partial sums (this lane's k-slice)
  auto compute = [&](int slot, int c) {
    const float* sp = ubuf + (slot << 13);
    const float* wp = Wsh + (c << 8);
    f32x4 u[8], w[8];
#pragma unroll
    for (int i = 0; i < 8; ++i) u[i] = *(const f32x4*)(sp + ((B0 + i) << 8) + k4);
#pragma unroll
    for (int i = 0; i < 8; ++i) w[i] = *(const f32x4*)(wp + ((R0 + i) << 10) + k4);
#pragma unroll
    for (int ri = 0; ri < 8; ++ri)
#pragma unroll
      for (int bi = 0; bi < 8; ++bi) {
        float t = fmaf(u[bi].x, w[ri].x, red[(ri << 3) + bi]);
        t = fmaf(u[bi].y, w[ri].y, t);
        t = fmaf(u[bi].z, w[ri].z, t);
        red[(ri << 3) + bi] = fmaf(u[bi].w, w[ri].w, t);
      }
  };

  asm volatile("s_waitcnt vmcnt(0) lgkmcnt(0)" ::: "memory");
  __builtin_amdgcn_sched_barrier(0);
  __builtin_amdgcn_s_barrier();   // Wsh visible

  f32x4 ra[4], rb[4];
  // s=0 prefetch (L1's y0[0] needs L0 step 0 done: per-lane producer polls)
  if (layer == 1) {
    poll_lane(flags0 + (lane << 5), 1);
    poll_lane(flags0 + ((64 + lane) << 5), 1);
  }
  issue(ra, 0, 0);
  issue(rb, 1, 0);

#pragma unroll 1
  for (int s = 0; s < TT; ++s) {
#pragma unroll
    for (int m = 0; m < 64; ++m) red[m] = 0.f;

    VMCNT4();                      // c0 landed (c1 in flight)
    stage(0, ra);
    LGKM0(); BAR();                // bar1
    if (s > 0) {                   // h[s-1]: poll exactly this lane's producers
      poll_lane(fl_own + (lane << 5), s);
      poll_lane(fl_own + ((64 + lane) << 5), s);
    }
    issue(ra, 2, s);               // c2 -> ra (c0 already staged); flies under c0/c1 compute
    compute(0, 0);

    VMCNT4();                      // c1 landed (c2 in flight)
    stage(1, rb);
    LGKM0(); BAR();                // bar2
    issue(rb, 3, s);               // c3 -> rb (c1 already staged)
    compute(1, 1);

    VMCNT4();                      // c2 landed (c3 in flight)
    stage(0, ra);
    LGKM0(); BAR();                // bar3
    compute(0, 2);

    VMCNT0();                      // c3 landed
    stage(1, rb);
    LGKM0(); BAR();                // bar4
    compute(1, 3);

    // butterfly reduce-with-redistribution: lane m ends owning gate m of this wave's tile
#pragma unroll
    for (int k = 0; k < 6; ++k) {
      const int bit = 1 << k;
      const bool hi = (lane & bit) != 0;
#pragma unroll
      for (int j = 0; j < (32 >> k); ++j) {
        const float a = red[2 * j], b = red[2 * j + 1];
        const float snd = hi ? a : b;
        const float rcv = __shfl_xor(snd, bit, 64);
        red[j] = (hi ? b : a) + rcv;
      }
    }
    // ring backpressure: L1 must have consumed the slot we are about to overwrite
    if (layer == 0 && s >= RING && tid < 128)
      poll_lane(flags1 + (tid << 5), s - RING + 1);
    gbuf[(R0 + (lane >> 3)) * 33 + (B0 + (lane & 7))] = red[0];
    LGKM0(); BAR();                // bar5: gbuf visible, backpressure certified

    float hn = 0.0f;
    int b_ = 0, jj_ = 0;
    if (tid < 128) {
      jj_ = tid & 3; b_ = tid >> 2;
      const float gi = gbuf[jj_ * 33 + b_]        + bias_[0];
      const float gf = gbuf[(4 + jj_) * 33 + b_]  + bias_[1];
      const float gg = gbuf[(8 + jj_) * 33 + b_]  + bias_[2];
      const float go = gbuf[(12 + jj_) * 33 + b_] + bias_[3];
      const float cn = sigf(gf) * creg + sigf(gi) * tanh_(gg);
      hn = sigf(go) * tanh_(cn);
      creg = cn;
      if (layer == 0)
        st_coh(ring + (size_t)(((s & 3) << 5) + b_) * 512 + j0 + jj_, hn);
      else
        st_coh(ring1 + (size_t)(((s & 3) << 5) + b_) * 512 + j0 + jj_, hn);
      asm volatile("s_waitcnt vmcnt(0)" ::: "memory");   // h stores drained (waves 0-1)
    }
    __builtin_amdgcn_sched_barrier(0);
    BAR();                         // bar6: all h stores certified; gbuf reads done
    if (tid == 0)
      __hip_atomic_store(fl_own + (lb << 5), s + 1, __ATOMIC_RELAXED, __HIP_MEMORY_SCOPE_AGENT);
    if (tid < 128) {               // non-consumed outputs: overlap with next step
      if (layer == 1) out[((size_t)((b_ << 11) + s) << 9) + j0 + jj_] = hn;
      if (s == TT - 1) out[(size_t)HFO + (size_t)(((layer << 5) + b_) << 9) + j0 + jj_] = hn;
    }
    if (s + 1 < TT) {              // prefetch next step's independent half
      if (layer == 1) {
        poll_lane(flags0 + (lane << 5), s + 2);
        poll_lane(flags0 + ((64 + lane) << 5), s + 2);
      }
      issue(ra, 0, s + 1);
      issue(rb, 1, s + 1);
    }
  }

  if (tid < 128)
    out[(size_t)CFO + (size_t)(((layer << 5) + (tid >> 2)) << 9) + j0 + (tid & 3)] = creg;
}

extern "C" void kernel_launch(void* const* d_in, const int* in_sizes, int n_in,
                              void* d_out, int out_size, void* d_ws, size_t ws_size,
                              hipStream_t stream) {
  (void)in_sizes; (void)n_in; (void)out_size; (void)ws_size;
  const float* x    = (const float*)d_in[0];
  const float* Wih0 = (const float*)d_in[1];
  const float* Whh0 = (const float*)d_in[2];
  const float* bih0 = (const float*)d_in[3];
  const float* bhh0 = (const float*)d_in[4];
  const float* Wih1 = (const float*)d_in[5];
  const float* Whh1 = (const float*)d_in[6];
  const float* bih1 = (const float*)d_in[7];
  const float* bhh1 = (const float*)d_in[8];
  const float* h0   = (const float*)d_in[9];
  const float* c0   = (const float*)d_in[10];

  float* out    = (float*)d_out;
  float* ring   = (float*)d_ws;                            // 256 KB
  float* ring1  = (float*)((char*)d_ws + (256 << 10));     // 256 KB
  int*   flags0 = (int*)((char*)d_ws + (512 << 10));       // 128 flags x 128 B
  int*   flags1 = (int*)((char*)d_ws + (528 << 10));       // 128 flags x 128 B

  // flags must be zero every call (graph replays don't re-poison)
  hipMemsetAsync(flags0, 0, 32 << 10, stream);

  hipLaunchKernelGGL(lstm_persist, dim3(2 * NBLK), dim3(512), 0, stream,
                     x, Wih0, Whh0, bih0, bhh0, Wih1, Whh1, bih1, bhh1,
                     h0, c0, out, ring, ring1, flags0, flags1);
}

// Round 5
// 28195.868 us; speedup vs baseline: 1.0619x; 1.0109x over previous
//
#include <hip/hip_runtime.h>

namespace {
constexpr int BB   = 32;    // batch
constexpr int TT   = 2048;  // time
constexpr int HH   = 512;   // hidden (== D)
constexpr int NBLK = 128;   // blocks per layer
constexpr int RING = 4;     // ring slots
constexpr int YSZ  = BB * TT * HH;
constexpr int HFO  = YSZ;
constexpr int CFO  = YSZ + 2 * BB * HH;
}

typedef float f32x4 __attribute__((ext_vector_type(4)));

__device__ __forceinline__ float sigf(float v)  { return 1.0f / (1.0f + __expf(-v)); }
__device__ __forceinline__ float tanh_(float v) { return 1.0f - 2.0f / (__expf(2.0f * v) + 1.0f); }

// plain cached 16B load (read-only inputs: x, h0)
__device__ __forceinline__ f32x4 ld_x4(const float* p) {
  f32x4 r;
  asm volatile("global_load_dwordx4 %0, %1, off" : "=v"(r) : "v"(p) : "memory");
  return r;
}
// agent-coherent 16B load (sc1: bypass L1/L2, hit shared coherence point)
__device__ __forceinline__ f32x4 ld_x4_coh(const float* p) {
  f32x4 r;
  asm volatile("global_load_dwordx4 %0, %1, off sc1" : "=v"(r) : "v"(p) : "memory");
  return r;
}
__device__ __forceinline__ void st_coh(float* p, float v) {
  __hip_atomic_store(p, v, __ATOMIC_RELAXED, __HIP_MEMORY_SCOPE_AGENT);
}
__device__ __forceinline__ void poll_lane(const int* f, int need) {
  while (__hip_atomic_load(f, __ATOMIC_RELAXED, __HIP_MEMORY_SCOPE_AGENT) < need)
    __builtin_amdgcn_s_sleep(1);
}

#define VMCNT4() do { asm volatile("s_waitcnt vmcnt(4)" ::: "memory"); __builtin_amdgcn_sched_barrier(0); } while (0)
#define VMCNT0() do { asm volatile("s_waitcnt vmcnt(0)" ::: "memory"); __builtin_amdgcn_sched_barrier(0); } while (0)
#define LGKM0()  do { asm volatile("s_waitcnt lgkmcnt(0)" ::: "memory"); __builtin_amdgcn_sched_barrier(0); } while (0)
#define BAR()    do { __builtin_amdgcn_s_barrier(); __builtin_amdgcn_sched_barrier(0); } while (0)

// launch_bounds(512, 2): 8 waves/block = 2 waves/SIMD -> 256-VGPR budget (m69),
// sized so red[64]+u/w[64]+ra/rb[32]+addr fits WITHOUT scratch spill (R4's 21 GB
// WRITE_SIZE was spill traffic from the compiler's 128-VGPR choice under (512,1)).
__global__ __launch_bounds__(512, 2) void lstm_persist(
    const float* __restrict__ x,
    const float* __restrict__ Wih0, const float* __restrict__ Whh0,
    const float* __restrict__ bih0, const float* __restrict__ bhh0,
    const float* __restrict__ Wih1, const float* __restrict__ Whh1,
    const float* __restrict__ bih1, const float* __restrict__ bhh1,
    const float* __restrict__ h0c, const float* __restrict__ c0c,
    float* __restrict__ out, float* __restrict__ ring, float* __restrict__ ring1,
    int* __restrict__ flags0, int* __restrict__ flags1)
{
  // LDS: W' 64 KB + double-buffered input slots 2x32 KB = 128 KB (1 block/CU).
  __shared__ __align__(16) float Wsh[16 * 1024];
  __shared__ __align__(16) float ubuf[2 * 32 * 256];
  float* gbuf = ubuf;  // alias of slot A; live only between bar5 and bar6

  const int tid   = (int)threadIdx.x;
  const int layer = (int)(blockIdx.x >> 7);
  const int lb    = (int)(blockIdx.x & (NBLK - 1));
  const int j0    = lb << 2;
  const int lane  = tid & 63;
  const int wg    = tid >> 6;          // wave id 0..7
  const int k4    = lane << 2;         // this lane's f32x4 within a 256-k chunk
  const int R0    = (wg & 1) << 3;     // 8-row group
  const int B0    = (wg >> 1) << 3;    // 8-batch group

  const float* Wih = layer ? Wih1 : Wih0;
  const float* Whh = layer ? Whh1 : Whh0;
  const float* bih = layer ? bih1 : bih0;
  const float* bhh = layer ? bhh1 : bhh0;
  int* fl_own = layer ? flags1 : flags0;   // h producers are always the own layer

  // ---- prologue: weights -> LDS (linear, conflict-free), bias, c0 ----
  for (int idx = tid; idx < 16 * 1024; idx += 512) {
    const int row = idx >> 10;           // 0..15 = gate*4 + jj
    const int k   = idx & 1023;
    const int rg  = ((row >> 2) << 9) + j0 + (row & 3);
    Wsh[(row << 10) + k] = (k < 512) ? Wih[(rg << 9) + k] : Whh[(rg << 9) + (k - 512)];
  }
  float creg = 0.0f;
  float bias_[4] = {0.f, 0.f, 0.f, 0.f};
  if (tid < 128) {
    const int jj = tid & 3;
    creg = c0c[layer * HH + j0 + jj];
#pragma unroll
    for (int g = 0; g < 4; ++g) {
      const int rg = (g << 9) + j0 + jj;
      bias_[g] = bih[rg] + bhh[rg];
    }
  }

  // chunk loader: 4 x f32x4 per thread; each f32x4 = 4 h-columns = ONE producer block
  auto issue = [&](f32x4* r, int c, int ss) {
#pragma unroll
    for (int i = 0; i < 4; ++i) {
      const int b = (i << 3) + wg;
      if (layer == 0) {
        if (c < 2)
          r[i] = ld_x4(x + ((size_t)((b << 11) + ss) << 9) + (c << 8) + k4);
        else if (ss == 0)
          r[i] = ld_x4(h0c + ((c - 2) << 8) + k4);
        else
          r[i] = ld_x4_coh(ring + (size_t)((((ss - 1) & 3) << 5) + b) * 512 + ((c - 2) << 8) + k4);
      } else {
        if (c < 2)
          r[i] = ld_x4_coh(ring + (size_t)(((ss & 3) << 5) + b) * 512 + (c << 8) + k4);
        else if (ss == 0)
          r[i] = ld_x4(h0c + 512 + ((c - 2) << 8) + k4);
        else
          r[i] = ld_x4_coh(ring1 + (size_t)((((ss - 1) & 3) << 5) + b) * 512 + ((c - 2) << 8) + k4);
      }
    }
  };
  auto stage = [&](int slot, const f32x4* r) {
    float* sp = ubuf + (slot << 13);
#pragma unroll
    for (int i = 0; i < 4; ++i)                       // contiguous 1024 B per wave: conflict-free
      *(f32x4*)(sp + ((((i << 3) + wg)) << 8) + k4) = r[i];
  };

  float red[64];  // 8 rows x 8 batches partial sums (this lane's k-slice)
  // FIRST=true overwrites red (skips the 64-mov zero-init each step)
  auto compute = [&](int slot, int c, bool first) {
    const float* sp = ubuf + (slot << 13);
    const float* wp = Wsh + (c << 8);
    f32x4 u[8], w[8];
#pragma unroll
    for (int i = 0; i < 8; ++i) u[i] = *(const f32x4*)(sp + ((B0 + i) << 8) + k4);
#pragma unroll
    for (int i = 0; i < 8; ++i) w[i] = *(const f32x4*)(wp + ((R0 + i) << 10) + k4);
#pragma unroll
    for (int ri = 0; ri < 8; ++ri)
#pragma unroll
      for (int bi = 0; bi < 8; ++bi) {
        float t = first ? u[bi].x * w[ri].x
                        : fmaf(u[bi].x, w[ri].x, red[(ri << 3) + bi]);
        t = fmaf(u[bi].y, w[ri].y, t);
        t = fmaf(u[bi].z, w[ri].z, t);
        red[(ri << 3) + bi] = fmaf(u[bi].w, w[ri].w, t);
      }
  };

  asm volatile("s_waitcnt vmcnt(0) lgkmcnt(0)" ::: "memory");
  __builtin_amdgcn_sched_barrier(0);
  __builtin_amdgcn_s_barrier();   // Wsh visible

  f32x4 ra[4], rb[4];
  // s=0 prefetch (L1's y0[0] needs L0 step 0 done: per-lane producer polls)
  if (layer == 1) {
    poll_lane(flags0 + (lane << 5), 1);
    poll_lane(flags0 + ((64 + lane) << 5), 1);
  }
  issue(ra, 0, 0);
  issue(rb, 1, 0);

#pragma unroll 1
  for (int s = 0; s < TT; ++s) {
    VMCNT4();                      // c0 landed (c1 in flight)
    stage(0, ra);
    LGKM0(); BAR();                // bar1
    if (s > 0) {                   // h[s-1]: poll exactly this lane's producers
      poll_lane(fl_own + (lane << 5), s);
      poll_lane(fl_own + ((64 + lane) << 5), s);
    }
    issue(ra, 2, s);               // c2 -> ra (c0 already staged); flies under c0/c1 compute
    compute(0, 0, true);

    VMCNT4();                      // c1 landed (c2 in flight)
    stage(1, rb);
    LGKM0(); BAR();                // bar2
    issue(rb, 3, s);               // c3 -> rb (c1 already staged)
    compute(1, 1, false);

    VMCNT4();                      // c2 landed (c3 in flight)
    stage(0, ra);
    LGKM0(); BAR();                // bar3
    compute(0, 2, false);

    VMCNT0();                      // c3 landed
    stage(1, rb);
    LGKM0(); BAR();                // bar4
    compute(1, 3, false);

    // butterfly reduce-with-redistribution: lane m ends owning gate m of this wave's tile
#pragma unroll
    for (int k = 0; k < 6; ++k) {
      const int bit = 1 << k;
      const bool hi = (lane & bit) != 0;
#pragma unroll
      for (int j = 0; j < (32 >> k); ++j) {
        const float a = red[2 * j], b = red[2 * j + 1];
        const float snd = hi ? a : b;
        const float rcv = __shfl_xor(snd, bit, 64);
        red[j] = (hi ? b : a) + rcv;
      }
    }
    // ring backpressure: L1 must have consumed the slot we are about to overwrite
    if (layer == 0 && s >= RING && tid < 128)
      poll_lane(flags1 + (tid << 5), s - RING + 1);
    gbuf[(R0 + (lane >> 3)) * 33 + (B0 + (lane & 7))] = red[0];
    LGKM0(); BAR();                // bar5: gbuf visible, backpressure certified

    float hn = 0.0f;
    int b_ = 0, jj_ = 0;
    if (tid < 128) {
      jj_ = tid & 3; b_ = tid >> 2;
      const float gi = gbuf[jj_ * 33 + b_]        + bias_[0];
      const float gf = gbuf[(4 + jj_) * 33 + b_]  + bias_[1];
      const float gg = gbuf[(8 + jj_) * 33 + b_]  + bias_[2];
      const float go = gbuf[(12 + jj_) * 33 + b_] + bias_[3];
      const float cn = sigf(gf) * creg + sigf(gi) * tanh_(gg);
      hn = sigf(go) * tanh_(cn);
      creg = cn;
      if (layer == 0)
        st_coh(ring + (size_t)(((s & 3) << 5) + b_) * 512 + j0 + jj_, hn);
      else
        st_coh(ring1 + (size_t)(((s & 3) << 5) + b_) * 512 + j0 + jj_, hn);
      asm volatile("s_waitcnt vmcnt(0)" ::: "memory");   // h stores drained (waves 0-1)
    }
    __builtin_amdgcn_sched_barrier(0);
    BAR();                         // bar6: all h stores certified; gbuf reads done
    if (tid == 0)
      __hip_atomic_store(fl_own + (lb << 5), s + 1, __ATOMIC_RELAXED, __HIP_MEMORY_SCOPE_AGENT);
    if (tid < 128) {               // non-consumed outputs: overlap with next step
      if (layer == 1) out[((size_t)((b_ << 11) + s) << 9) + j0 + jj_] = hn;
      if (s == TT - 1) out[(size_t)HFO + (size_t)(((layer << 5) + b_) << 9) + j0 + jj_] = hn;
    }
    if (s + 1 < TT) {              // prefetch next step's independent half
      if (layer == 1) {
        poll_lane(flags0 + (lane << 5), s + 2);
        poll_lane(flags0 + ((64 + lane) << 5), s + 2);
      }
      issue(ra, 0, s + 1);
      issue(rb, 1, s + 1);
    }
  }

  if (tid < 128)
    out[(size_t)CFO + (size_t)(((layer << 5) + (tid >> 2)) << 9) + j0 + (tid & 3)] = creg;
}

extern "C" void kernel_launch(void* const* d_in, const int* in_sizes, int n_in,
                              void* d_out, int out_size, void* d_ws, size_t ws_size,
                              hipStream_t stream) {
  (void)in_sizes; (void)n_in; (void)out_size; (void)ws_size;
  const float* x    = (const float*)d_in[0];
  const float* Wih0 = (const float*)d_in[1];
  const float* Whh0 = (const float*)d_in[2];
  const float* bih0 = (const float*)d_in[3];
  const float* bhh0 = (const float*)d_in[4];
  const float* Wih1 = (const float*)d_in[5];
  const float* Whh1 = (const float*)d_in[6];
  const float* bih1 = (const float*)d_in[7];
  const float* bhh1 = (const float*)d_in[8];
  const float* h0   = (const float*)d_in[9];
  const float* c0   = (const float*)d_in[10];

  float* out    = (float*)d_out;
  float* ring   = (float*)d_ws;                            // 256 KB
  float* ring1  = (float*)((char*)d_ws + (256 << 10));     // 256 KB
  int*   flags0 = (int*)((char*)d_ws + (512 << 10));       // 128 flags x 128 B
  int*   flags1 = (int*)((char*)d_ws + (528 << 10));       // 128 flags x 128 B

  // flags must be zero every call (graph replays don't re-poison)
  hipMemsetAsync(flags0, 0, 32 << 10, stream);

  hipLaunchKernelGGL(lstm_persist, dim3(2 * NBLK), dim3(512), 0, stream,
                     x, Wih0, Whh0, bih0, bhh0, Wih1, Whh1, bih1, bhh1,
                     h0, c0, out, ring, ring1, flags0, flags1);
}